// Round 7
// baseline (73.642 us; speedup 1.0000x reference)
//
#include <hip/hip_runtime.h>

constexpr int B = 8, N = 1024, FIN = 128, FOUT = 64, H = 4;
constexpr float LOG2E = 1.44269504f;

typedef __attribute__((ext_vector_type(8))) short short8;
typedef __attribute__((ext_vector_type(4))) short short4v;
typedef __attribute__((ext_vector_type(4))) float f32x4;

// f32 -> bf16 round-to-nearest-even (prep-kernel use only)
static __device__ inline unsigned short f2bf(float x) {
    union { float f; unsigned u; } v; v.f = x;
    unsigned r = v.u + 0x7fff + ((v.u >> 16) & 1);
    return (unsigned short)(r >> 16);
}

// ---------------------------------------------------------------------------
// mb[i][j] = adj ? LOG2E*bias : -1e35   (f32 — R5-verified path; fp16 variant
// produced NaN in R6 and is quarantined until bisected)
// ---------------------------------------------------------------------------
__global__ __launch_bounds__(256) void mb_prep(
    const int* __restrict__ adj, const float* __restrict__ bias,
    float* __restrict__ mb)
{
    int idx = blockIdx.x * 256 + threadIdx.x;   // over N*N/4
    int4   a4 = reinterpret_cast<const int4*>(adj)[idx];
    float4 b4 = reinterpret_cast<const float4*>(bias)[idx];
    float4 o;
    o.x = a4.x ? LOG2E * b4.x : -1e35f;
    o.y = a4.y ? LOG2E * b4.y : -1e35f;
    o.z = a4.z ? LOG2E * b4.z : -1e35f;
    o.w = a4.w ? LOG2E * b4.w : -1e35f;
    reinterpret_cast<float4*>(mb)[idx] = o;
}

// ---------------------------------------------------------------------------
// Kernel A: h_prime GEMM + ei/ej (prescaled by LOG2E). Unchanged (verified).
// ---------------------------------------------------------------------------
__global__ __launch_bounds__(256) void gat_prep(
    const float* __restrict__ h,      // (B,N,FIN)
    const float* __restrict__ W,      // (H,FIN,FOUT)
    const float* __restrict__ a,      // (H,2*FOUT,1)
    unsigned short* __restrict__ hpT, // (B,H,64,N) bf16
    float* __restrict__ ei_t,         // (B,H,N) *LOG2E
    float* __restrict__ ej_t)         // (B,H,N) *LOG2E
{
    __shared__ float h_lds[8][132];
    const int t   = threadIdx.x;
    const int blk = blockIdx.x;
    const int b   = blk >> 7;
    const int n0  = (blk & 127) * 8;

    {
        const float* src = h + ((size_t)b * N + n0) * FIN;
        float4 x = reinterpret_cast<const float4*>(src)[t];
        int fl = t * 4;
        *reinterpret_cast<float4*>(&h_lds[fl >> 7][fl & 127]) = x;
    }
    __syncthreads();

    const int hd   = t >> 6;
    const int lane = t & 63;
    const int f0   = (lane & 15) * 4;
    const int g    = (lane >> 4) & 1;
    const int kh   = lane >> 5;

    float acc[4][4];
    #pragma unroll
    for (int k = 0; k < 4; ++k)
        #pragma unroll
        for (int j = 0; j < 4; ++j) acc[k][j] = 0.f;

    const float* Wp = W + (size_t)hd * FIN * FOUT + (size_t)kh * 64 * FOUT + f0;
    #pragma unroll 4
    for (int i = 0; i < 64; ++i) {
        float4 w4 = *reinterpret_cast<const float4*>(Wp + (size_t)i * FOUT);
        #pragma unroll
        for (int k = 0; k < 4; ++k) {
            float hv = h_lds[4 * g + k][kh * 64 + i];
            acc[k][0] = fmaf(hv, w4.x, acc[k][0]);
            acc[k][1] = fmaf(hv, w4.y, acc[k][1]);
            acc[k][2] = fmaf(hv, w4.z, acc[k][2]);
            acc[k][3] = fmaf(hv, w4.w, acc[k][3]);
        }
    }

    #pragma unroll
    for (int k = 0; k < 4; ++k)
        #pragma unroll
        for (int j = 0; j < 4; ++j)
            acc[k][j] += __shfl_xor(acc[k][j], 32, 64);

    const int bh = b * H + hd;
    if (kh == 0) {
        #pragma unroll
        for (int jj = 0; jj < 4; ++jj) {
            short4v v4;
            v4[0] = (short)f2bf(acc[0][jj]);
            v4[1] = (short)f2bf(acc[1][jj]);
            v4[2] = (short)f2bf(acc[2][jj]);
            v4[3] = (short)f2bf(acc[3][jj]);
            *reinterpret_cast<short4v*>(
                hpT + ((size_t)bh * 64 + f0 + jj) * N + n0 + 4 * g) = v4;
        }
    }

    float4 a1 = *reinterpret_cast<const float4*>(a + (size_t)hd * 2 * FOUT + f0);
    float4 a2 = *reinterpret_cast<const float4*>(a + (size_t)hd * 2 * FOUT + FOUT + f0);
    #pragma unroll
    for (int k = 0; k < 4; ++k) {
        float e1 = acc[k][0] * a1.x + acc[k][1] * a1.y + acc[k][2] * a1.z + acc[k][3] * a1.w;
        float e2 = acc[k][0] * a2.x + acc[k][1] * a2.y + acc[k][2] * a2.z + acc[k][3] * a2.w;
        #pragma unroll
        for (int m = 1; m < 16; m <<= 1) {
            e1 += __shfl_xor(e1, m, 64);
            e2 += __shfl_xor(e2, m, 64);
        }
        // group-g's full sum sits on lane 16*g of the kh=0 half
        if ((lane & 15) == 0 && kh == 0) {
            int r = n0 + 4 * g + k;
            ei_t[(size_t)bh * N + r] = LOG2E * e1;
            ej_t[(size_t)bh * N + r] = LOG2E * e2;
        }
    }
}

// ---------------------------------------------------------------------------
// Kernel B: fused scores+softmax+PV. Block = (bh, 64 i-rows); wave w owns
// i-subtile w over ALL j (scores once, no LDS, no barrier). Bijective XCD
// swizzle co-locates 8 bh-slabs x 8 i-tiles per XCD (mb 2MB + hpT 1MB fits
// the 4MB L2). Row sums via all-ones MFMA (c4[r] = sum for exactly the rows
// this lane writes) -> register-local normalization. Depth-1 prefetch.
// ---------------------------------------------------------------------------
__global__ __launch_bounds__(256) void gat_attn(
    const unsigned short* __restrict__ hpT, // (B,H,64,N) bf16
    const float* __restrict__ ei_t,         // (B,H,N) *LOG2E
    const float* __restrict__ ej_t,         // (B,H,N) *LOG2E
    const float* __restrict__ mb,           // (N,N) masked bias *LOG2E
    float* __restrict__ out)                // (B,N,H*FOUT)
{
    const int raw  = blockIdx.x;            // 512
    const int xcd  = raw & 7;               // dispatcher XCD = raw % 8
    const int k_   = raw >> 3;              // [0,64)
    const int bh   = ((xcd >> 1) << 3) | (k_ >> 3);   // 8 bh per XCD
    const int i0   = ((((xcd & 1) << 3) | (k_ & 7))) * 64;  // 8 i-tiles per XCD
    const int t    = threadIdx.x;
    const int w    = t >> 6;                // i-subtile within the 64 rows
    const int lane = t & 63;
    const int li   = lane & 15;
    const int kg   = lane >> 4;
    const int irow = i0 + w * 16 + li;      // this lane's A-fragment row

    const float  ei0   = ei_t[(size_t)bh * N + irow];
    const float* ejrow = ej_t + (size_t)bh * N;
    const float* mbrow = mb + (size_t)irow * N;
    const unsigned short* bp = hpT + ((size_t)bh * 64 + li) * N;

    f32x4 c0 = {0.f,0.f,0.f,0.f}, c1 = {0.f,0.f,0.f,0.f};
    f32x4 c2 = {0.f,0.f,0.f,0.f}, c3 = {0.f,0.f,0.f,0.f};
    f32x4 c4 = {0.f,0.f,0.f,0.f};
    const short obf = (short)0x3F80;                      // bf16 1.0
    const short8 ones = {obf,obf,obf,obf,obf,obf,obf,obf};

    #define DECLS(S) float4 ejA##S, ejB##S, mA##S, mB##S; \
                     short8 bA##S, bB##S, bC##S, bD##S;
    #define LOADS(S, JC) { const int jo_ = (JC) * 32 + 8 * kg;               \
        ejA##S = *reinterpret_cast<const float4*>(ejrow + jo_);              \
        ejB##S = *reinterpret_cast<const float4*>(ejrow + jo_ + 4);          \
        mA##S  = *reinterpret_cast<const float4*>(mbrow + jo_);              \
        mB##S  = *reinterpret_cast<const float4*>(mbrow + jo_ + 4);          \
        bA##S  = *reinterpret_cast<const short8*>(bp + jo_);                 \
        bB##S  = *reinterpret_cast<const short8*>(bp + 16 * N + jo_);        \
        bC##S  = *reinterpret_cast<const short8*>(bp + 32 * N + jo_);        \
        bD##S  = *reinterpret_cast<const short8*>(bp + 48 * N + jo_); }
    #define SCORE(PD, EJ, MBV) {                                             \
        float e_ = ei0 + (EJ);                                               \
        e_ = fmaxf(e_, 0.2f * e_) + (MBV);                                   \
        asm("v_exp_f32 %0, %1" : "=v"(PD) : "v"(e_)); }
    #define COMPS(S) {                                                       \
        float p0,p1,p2,p3,p4,p5,p6,p7;                                       \
        SCORE(p0, ejA##S.x, mA##S.x) SCORE(p1, ejA##S.y, mA##S.y)            \
        SCORE(p2, ejA##S.z, mA##S.z) SCORE(p3, ejA##S.w, mA##S.w)            \
        SCORE(p4, ejB##S.x, mB##S.x) SCORE(p5, ejB##S.y, mB##S.y)            \
        SCORE(p6, ejB##S.z, mB##S.z) SCORE(p7, ejB##S.w, mB##S.w)            \
        int4 pk_;                                                            \
        asm("v_cvt_pk_bf16_f32 %0, %1, %2" : "=v"(pk_.x) : "v"(p0), "v"(p1));\
        asm("v_cvt_pk_bf16_f32 %0, %1, %2" : "=v"(pk_.y) : "v"(p2), "v"(p3));\
        asm("v_cvt_pk_bf16_f32 %0, %1, %2" : "=v"(pk_.z) : "v"(p4), "v"(p5));\
        asm("v_cvt_pk_bf16_f32 %0, %1, %2" : "=v"(pk_.w) : "v"(p6), "v"(p7));\
        short8 a0_ = *reinterpret_cast<short8*>(&pk_);                       \
        c0 = __builtin_amdgcn_mfma_f32_16x16x32_bf16(a0_, bA##S, c0, 0,0,0); \
        c1 = __builtin_amdgcn_mfma_f32_16x16x32_bf16(a0_, bB##S, c1, 0,0,0); \
        c2 = __builtin_amdgcn_mfma_f32_16x16x32_bf16(a0_, bC##S, c2, 0,0,0); \
        c3 = __builtin_amdgcn_mfma_f32_16x16x32_bf16(a0_, bD##S, c3, 0,0,0); \
        c4 = __builtin_amdgcn_mfma_f32_16x16x32_bf16(a0_, ones,  c4, 0,0,0); }

    DECLS(0) DECLS(1)
    LOADS(0, 0)
    #pragma unroll 2
    for (int jc = 0; jc < 32; jc += 2) {
        LOADS(1, jc + 1)
        COMPS(0)
        if (jc + 2 < 32) LOADS(0, jc + 2)
        COMPS(1)
    }
    #undef DECLS
    #undef LOADS
    #undef SCORE
    #undef COMPS

    // C layout col=li (f within tile), row=4*kg+r; c4[r] = that row's sum.
    const int b  = bh >> 2;
    const int hd = bh & 3;
    #pragma unroll
    for (int r = 0; r < 4; ++r) {
        int orow = i0 + w * 16 + 4 * kg + r;
        float inv = 1.0f / c4[r];
        float* ob = out + (((size_t)b * N + orow) * H + hd) * 64 + li;
        ob[0]  = c0[r] * inv;
        ob[16] = c1[r] * inv;
        ob[32] = c2[r] * inv;
        ob[48] = c3[r] * inv;
    }
}

extern "C" void kernel_launch(void* const* d_in, const int* in_sizes, int n_in,
                              void* d_out, int out_size, void* d_ws, size_t ws_size,
                              hipStream_t stream) {
    const float* h    = (const float*)d_in[0];
    const int*   adj  = (const int*)  d_in[1];
    const float* bias = (const float*)d_in[2];
    const float* W    = (const float*)d_in[3];
    const float* a    = (const float*)d_in[4];
    float* out = (float*)d_out;

    char* ws = (char*)d_ws;
    unsigned short* hpT = (unsigned short*)ws;                    // 4 MB
    float* mb   = (float*)(ws + (size_t)B * H * 64 * N * 2);      // 4 MB
    float* ei_t = (float*)(ws + (size_t)B * H * 64 * N * 2 + (size_t)N * N * 4);
    float* ej_t = ei_t + (size_t)B * H * N;

    mb_prep<<<N * N / 4 / 256, 256, 0, stream>>>(adj, bias, mb);
    gat_prep<<<B * N / 8, 256, 0, stream>>>(h, W, a, hpT, ei_t, ej_t);
    gat_attn<<<B * H * (N / 64), 256, 0, stream>>>(hpT, ei_t, ej_t, mb, out);
}

// Round 8
// 44.318 us; speedup vs baseline: 1.6617x; 1.6617x over previous
//
#include <hip/hip_runtime.h>

constexpr int B = 8, N = 1024, FIN = 128, FOUT = 64, H = 4;
constexpr float LOG2E = 1.44269504f;

typedef __attribute__((ext_vector_type(8))) short short8;
typedef __attribute__((ext_vector_type(4))) short short4v;
typedef __attribute__((ext_vector_type(4))) float f32x4;

// f32 -> bf16 round-to-nearest-even (prep-kernel use only)
static __device__ inline unsigned short f2bf(float x) {
    union { float f; unsigned u; } v; v.f = x;
    unsigned r = v.u + 0x7fff + ((v.u >> 16) & 1);
    return (unsigned short)(r >> 16);
}

// ---------------------------------------------------------------------------
// mbF[ti][jc][lane][e] = adj ? LOG2E*bias : -1e35, in A-FRAGMENT ORDER:
//   value for (i = ti*16 + (lane&15), j = jc*32 + 8*(lane>>4) + e).
// gat_attn then loads it as base + lane*32B + jc*2KB: fully coalesced.
// Reads here are 16-row-strided but this kernel is small and write-coalesced.
// ---------------------------------------------------------------------------
__global__ __launch_bounds__(256) void mb_prep(
    const int* __restrict__ adj, const float* __restrict__ bias,
    float* __restrict__ mbF)
{
    const int bx   = blockIdx.x;            // 512
    const int t    = threadIdx.x;
    const int ti   = bx >> 3;               // 64 i-tiles
    const int jc   = (bx & 7) * 4 + (t >> 6);
    const int lane = t & 63;
    const int i    = ti * 16 + (lane & 15);
    const int j0   = jc * 32 + 8 * (lane >> 4);

    const int4*   ap = reinterpret_cast<const int4*>(adj + (size_t)i * N + j0);
    const float4* bp = reinterpret_cast<const float4*>(bias + (size_t)i * N + j0);
    int4   a0 = ap[0], a1 = ap[1];
    float4 b0 = bp[0], b1 = bp[1];
    float4 o0, o1;
    o0.x = a0.x ? LOG2E * b0.x : -1e35f;
    o0.y = a0.y ? LOG2E * b0.y : -1e35f;
    o0.z = a0.z ? LOG2E * b0.z : -1e35f;
    o0.w = a0.w ? LOG2E * b0.w : -1e35f;
    o1.x = a1.x ? LOG2E * b1.x : -1e35f;
    o1.y = a1.y ? LOG2E * b1.y : -1e35f;
    o1.z = a1.z ? LOG2E * b1.z : -1e35f;
    o1.w = a1.w ? LOG2E * b1.w : -1e35f;

    float* dst = mbF + (((size_t)ti * 32 + jc) * 64 + lane) * 8;
    *reinterpret_cast<float4*>(dst)     = o0;
    *reinterpret_cast<float4*>(dst + 4) = o1;
}

// ---------------------------------------------------------------------------
// Kernel A: h_prime GEMM + ei/ej (prescaled by LOG2E). Math unchanged
// (verified R5/R7); hp output now in B-FRAGMENT ORDER:
//   hpF[bh][jc][ft][lane][e] = hp(f = ft*16 + (lane&15), n = jc*32 + 8*(lane>>4)+e)
// ---------------------------------------------------------------------------
__global__ __launch_bounds__(256) void gat_prep(
    const float* __restrict__ h,      // (B,N,FIN)
    const float* __restrict__ W,      // (H,FIN,FOUT)
    const float* __restrict__ a,      // (H,2*FOUT,1)
    unsigned short* __restrict__ hpF, // fragment-order bf16 (4 MB)
    float* __restrict__ ei_t,         // (B,H,N) *LOG2E
    float* __restrict__ ej_t)         // (B,H,N) *LOG2E
{
    __shared__ float h_lds[8][132];
    const int t   = threadIdx.x;
    const int blk = blockIdx.x;
    const int b   = blk >> 7;
    const int n0  = (blk & 127) * 8;

    {
        const float* src = h + ((size_t)b * N + n0) * FIN;
        float4 x = reinterpret_cast<const float4*>(src)[t];
        int fl = t * 4;
        *reinterpret_cast<float4*>(&h_lds[fl >> 7][fl & 127]) = x;
    }
    __syncthreads();

    const int hd   = t >> 6;
    const int lane = t & 63;
    const int li   = lane & 15;
    const int f0   = li * 4;
    const int g    = (lane >> 4) & 1;
    const int kh   = lane >> 5;

    float acc[4][4];
    #pragma unroll
    for (int k = 0; k < 4; ++k)
        #pragma unroll
        for (int j = 0; j < 4; ++j) acc[k][j] = 0.f;

    const float* Wp = W + (size_t)hd * FIN * FOUT + (size_t)kh * 64 * FOUT + f0;
    #pragma unroll 4
    for (int i = 0; i < 64; ++i) {
        float4 w4 = *reinterpret_cast<const float4*>(Wp + (size_t)i * FOUT);
        #pragma unroll
        for (int k = 0; k < 4; ++k) {
            float hv = h_lds[4 * g + k][kh * 64 + i];
            acc[k][0] = fmaf(hv, w4.x, acc[k][0]);
            acc[k][1] = fmaf(hv, w4.y, acc[k][1]);
            acc[k][2] = fmaf(hv, w4.z, acc[k][2]);
            acc[k][3] = fmaf(hv, w4.w, acc[k][3]);
        }
    }

    #pragma unroll
    for (int k = 0; k < 4; ++k)
        #pragma unroll
        for (int j = 0; j < 4; ++j)
            acc[k][j] += __shfl_xor(acc[k][j], 32, 64);

    const int bh = b * H + hd;
    if (kh == 0) {
        // rows n = n0+4g+k (k=0..3), f = f0+jj. Fragment coords:
        //   jc = n0>>5, kgp = (n0>>3)&3, e = 4g+k, ft = li>>2,
        //   lane' = ((4*(li&3))+jj) + 16*kgp
        const int jc  = n0 >> 5;
        const int kgp = (n0 >> 3) & 3;
        const int ft  = li >> 2;
        const int e0  = 4 * g;
        #pragma unroll
        for (int jj = 0; jj < 4; ++jj) {
            short4v v4;
            v4[0] = (short)f2bf(acc[0][jj]);
            v4[1] = (short)f2bf(acc[1][jj]);
            v4[2] = (short)f2bf(acc[2][jj]);
            v4[3] = (short)f2bf(acc[3][jj]);
            const int lanep = (4 * (li & 3) + jj) + 16 * kgp;
            *reinterpret_cast<short4v*>(
                hpF + ((((size_t)bh * 32 + jc) * 4 + ft) * 64 + lanep) * 8 + e0) = v4;
        }
    }

    float4 a1 = *reinterpret_cast<const float4*>(a + (size_t)hd * 2 * FOUT + f0);
    float4 a2 = *reinterpret_cast<const float4*>(a + (size_t)hd * 2 * FOUT + FOUT + f0);
    #pragma unroll
    for (int k = 0; k < 4; ++k) {
        float e1 = acc[k][0] * a1.x + acc[k][1] * a1.y + acc[k][2] * a1.z + acc[k][3] * a1.w;
        float e2 = acc[k][0] * a2.x + acc[k][1] * a2.y + acc[k][2] * a2.z + acc[k][3] * a2.w;
        #pragma unroll
        for (int m = 1; m < 16; m <<= 1) {
            e1 += __shfl_xor(e1, m, 64);
            e2 += __shfl_xor(e2, m, 64);
        }
        // group-g's full sum sits on lane 16*g of the kh=0 half
        if ((lane & 15) == 0 && kh == 0) {
            int r = n0 + 4 * g + k;
            ei_t[(size_t)bh * N + r] = LOG2E * e1;
            ej_t[(size_t)bh * N + r] = LOG2E * e2;
        }
    }
}

// ---------------------------------------------------------------------------
// Kernel B: fused scores+softmax+PV. Structure as R7 (64-row blocks, no LDS,
// c4 ones-MFMA row sums, XCD swizzle, depth-1 prefetch), but mbF/hpF are in
// fragment order -> every hot load is base + lane*(32B|16B) + jc*const:
// fully coalesced, immediate-offset addressable.
// ---------------------------------------------------------------------------
__global__ __launch_bounds__(256) void gat_attn(
    const unsigned short* __restrict__ hpF, // fragment-order bf16
    const float* __restrict__ ei_t,         // (B,H,N) *LOG2E
    const float* __restrict__ ej_t,         // (B,H,N) *LOG2E
    const float* __restrict__ mbF,          // fragment-order f32
    float* __restrict__ out)                // (B,N,H*FOUT)
{
    const int raw  = blockIdx.x;            // 512
    const int xcd  = raw & 7;
    const int k_   = raw >> 3;
    const int bh   = ((xcd >> 1) << 3) | (k_ >> 3);          // 8 bh per XCD
    const int it0  = (((xcd & 1) << 3) | (k_ & 7)) * 4;      // first of 4 i-tiles
    const int t    = threadIdx.x;
    const int w    = t >> 6;
    const int lane = t & 63;
    const int li   = lane & 15;
    const int kg   = lane >> 4;
    const int ti   = it0 + w;
    const int irow = ti * 16 + li;

    const float  ei0   = ei_t[(size_t)bh * N + irow];
    const float* ejrow = ej_t + (size_t)bh * N;
    const float* mrow  = mbF + ((size_t)ti * 32 * 64 + lane) * 8;       // + jc*512
    const unsigned short* hrow = hpF + ((size_t)bh * 32 * 4 * 64 + lane) * 8; // + jc*2048 + ft*512

    f32x4 c0 = {0.f,0.f,0.f,0.f}, c1 = {0.f,0.f,0.f,0.f};
    f32x4 c2 = {0.f,0.f,0.f,0.f}, c3 = {0.f,0.f,0.f,0.f};
    f32x4 c4 = {0.f,0.f,0.f,0.f};
    const short obf = (short)0x3F80;                      // bf16 1.0
    const short8 ones = {obf,obf,obf,obf,obf,obf,obf,obf};

    #define DECLS(S) float4 ejA##S, ejB##S, mA##S, mB##S; \
                     short8 bA##S, bB##S, bC##S, bD##S;
    #define LOADS(S, JC) {                                                   \
        ejA##S = *reinterpret_cast<const float4*>(ejrow + (JC) * 32 + 8 * kg);\
        ejB##S = *reinterpret_cast<const float4*>(ejrow + (JC) * 32 + 8 * kg + 4);\
        mA##S  = *reinterpret_cast<const float4*>(mrow + (JC) * 512);        \
        mB##S  = *reinterpret_cast<const float4*>(mrow + (JC) * 512 + 4);    \
        bA##S  = *reinterpret_cast<const short8*>(hrow + (JC) * 2048);       \
        bB##S  = *reinterpret_cast<const short8*>(hrow + (JC) * 2048 + 512); \
        bC##S  = *reinterpret_cast<const short8*>(hrow + (JC) * 2048 + 1024);\
        bD##S  = *reinterpret_cast<const short8*>(hrow + (JC) * 2048 + 1536); }
    #define SCORE(PD, EJ, MBV) {                                             \
        float e_ = ei0 + (EJ);                                               \
        e_ = fmaxf(e_, 0.2f * e_) + (MBV);                                   \
        asm("v_exp_f32 %0, %1" : "=v"(PD) : "v"(e_)); }
    #define COMPS(S) {                                                       \
        float p0,p1,p2,p3,p4,p5,p6,p7;                                       \
        SCORE(p0, ejA##S.x, mA##S.x) SCORE(p1, ejA##S.y, mA##S.y)            \
        SCORE(p2, ejA##S.z, mA##S.z) SCORE(p3, ejA##S.w, mA##S.w)            \
        SCORE(p4, ejB##S.x, mB##S.x) SCORE(p5, ejB##S.y, mB##S.y)            \
        SCORE(p6, ejB##S.z, mB##S.z) SCORE(p7, ejB##S.w, mB##S.w)            \
        int4 pk_;                                                            \
        asm("v_cvt_pk_bf16_f32 %0, %1, %2" : "=v"(pk_.x) : "v"(p0), "v"(p1));\
        asm("v_cvt_pk_bf16_f32 %0, %1, %2" : "=v"(pk_.y) : "v"(p2), "v"(p3));\
        asm("v_cvt_pk_bf16_f32 %0, %1, %2" : "=v"(pk_.z) : "v"(p4), "v"(p5));\
        asm("v_cvt_pk_bf16_f32 %0, %1, %2" : "=v"(pk_.w) : "v"(p6), "v"(p7));\
        short8 a0_ = *reinterpret_cast<short8*>(&pk_);                       \
        c0 = __builtin_amdgcn_mfma_f32_16x16x32_bf16(a0_, bA##S, c0, 0,0,0); \
        c1 = __builtin_amdgcn_mfma_f32_16x16x32_bf16(a0_, bB##S, c1, 0,0,0); \
        c2 = __builtin_amdgcn_mfma_f32_16x16x32_bf16(a0_, bC##S, c2, 0,0,0); \
        c3 = __builtin_amdgcn_mfma_f32_16x16x32_bf16(a0_, bD##S, c3, 0,0,0); \
        c4 = __builtin_amdgcn_mfma_f32_16x16x32_bf16(a0_, ones,  c4, 0,0,0); }

    DECLS(0) DECLS(1)
    LOADS(0, 0)
    #pragma unroll 2
    for (int jc = 0; jc < 32; jc += 2) {
        LOADS(1, jc + 1)
        COMPS(0)
        if (jc + 2 < 32) LOADS(0, jc + 2)
        COMPS(1)
    }
    #undef DECLS
    #undef LOADS
    #undef SCORE
    #undef COMPS

    // C layout col=li (f within tile), row=4*kg+r; c4[r] = that row's sum.
    const int b  = bh >> 2;
    const int hd = bh & 3;
    #pragma unroll
    for (int r = 0; r < 4; ++r) {
        int orow = ti * 16 + 4 * kg + r;
        float inv = 1.0f / c4[r];
        float* ob = out + (((size_t)b * N + orow) * H + hd) * 64 + li;
        ob[0]  = c0[r] * inv;
        ob[16] = c1[r] * inv;
        ob[32] = c2[r] * inv;
        ob[48] = c3[r] * inv;
    }
}

extern "C" void kernel_launch(void* const* d_in, const int* in_sizes, int n_in,
                              void* d_out, int out_size, void* d_ws, size_t ws_size,
                              hipStream_t stream) {
    const float* h    = (const float*)d_in[0];
    const int*   adj  = (const int*)  d_in[1];
    const float* bias = (const float*)d_in[2];
    const float* W    = (const float*)d_in[3];
    const float* a    = (const float*)d_in[4];
    float* out = (float*)d_out;

    char* ws = (char*)d_ws;
    unsigned short* hpF = (unsigned short*)ws;                    // 4 MB
    float* mbF  = (float*)(ws + (size_t)B * H * 64 * N * 2);      // 4 MB
    float* ei_t = (float*)(ws + (size_t)B * H * 64 * N * 2 + (size_t)N * N * 4);
    float* ej_t = ei_t + (size_t)B * H * N;

    mb_prep<<<512, 256, 0, stream>>>(adj, bias, mbF);
    gat_prep<<<B * N / 8, 256, 0, stream>>>(h, W, a, hpF, ei_t, ej_t);
    gat_attn<<<B * H * (N / 64), 256, 0, stream>>>(hpF, ei_t, ej_t, mbF, out);
}

// Round 9
// 42.567 us; speedup vs baseline: 1.7300x; 1.0411x over previous
//
#include <hip/hip_runtime.h>

constexpr int B = 8, N = 1024, FIN = 128, FOUT = 64, H = 4;
constexpr float LOG2E = 1.44269504f;

typedef __attribute__((ext_vector_type(8))) short short8;
typedef __attribute__((ext_vector_type(4))) short short4v;
typedef __attribute__((ext_vector_type(4))) float f32x4;

// f32 -> bf16 round-to-nearest-even (prep-kernel use only)
static __device__ inline unsigned short f2bf(float x) {
    union { float f; unsigned u; } v; v.f = x;
    unsigned r = v.u + 0x7fff + ((v.u >> 16) & 1);
    return (unsigned short)(r >> 16);
}

// ---------------------------------------------------------------------------
// Fused prep kernel. Blocks 0..511: mbF (A-fragment-order masked bias).
// Blocks 512..1535: h_prime GEMM + ei/ej (identical math to R8-verified).
//   mbF[ti][jc][lane][e] = (i=ti*16+(lane&15), j=jc*32+8*(lane>>4)+e)
//   hpF[bh][jc][ft][lane][e] = hp(f=ft*16+(lane&15), n=jc*32+8*(lane>>4)+e)
// The two halves are independent; fusing removes a launch/serialization gap.
// ---------------------------------------------------------------------------
__global__ __launch_bounds__(256) void gat_prep(
    const float* __restrict__ h,      // (B,N,FIN)
    const float* __restrict__ W,      // (H,FIN,FOUT)
    const float* __restrict__ a,      // (H,2*FOUT,1)
    const int*   __restrict__ adj,    // (N,N)
    const float* __restrict__ bias,   // (N,N)
    unsigned short* __restrict__ hpF, // fragment-order bf16 (4 MB)
    float* __restrict__ mbF,          // fragment-order f32 (4 MB)
    float* __restrict__ ei_t,         // (B,H,N) *LOG2E
    float* __restrict__ ej_t)         // (B,H,N) *LOG2E
{
    __shared__ float h_lds[8][132];
    const int t = threadIdx.x;

    if (blockIdx.x < 512) {           // ---- mb part ----
        const int bx   = blockIdx.x;
        const int ti   = bx >> 3;
        const int jc   = (bx & 7) * 4 + (t >> 6);
        const int lane = t & 63;
        const int i    = ti * 16 + (lane & 15);
        const int j0   = jc * 32 + 8 * (lane >> 4);

        const int4*   ap = reinterpret_cast<const int4*>(adj + (size_t)i * N + j0);
        const float4* bp = reinterpret_cast<const float4*>(bias + (size_t)i * N + j0);
        int4   a0 = ap[0], a1 = ap[1];
        float4 b0 = bp[0], b1 = bp[1];
        float4 o0, o1;
        o0.x = a0.x ? LOG2E * b0.x : -1e35f;
        o0.y = a0.y ? LOG2E * b0.y : -1e35f;
        o0.z = a0.z ? LOG2E * b0.z : -1e35f;
        o0.w = a0.w ? LOG2E * b0.w : -1e35f;
        o1.x = a1.x ? LOG2E * b1.x : -1e35f;
        o1.y = a1.y ? LOG2E * b1.y : -1e35f;
        o1.z = a1.z ? LOG2E * b1.z : -1e35f;
        o1.w = a1.w ? LOG2E * b1.w : -1e35f;

        float* dst = mbF + (((size_t)ti * 32 + jc) * 64 + lane) * 8;
        *reinterpret_cast<float4*>(dst)     = o0;
        *reinterpret_cast<float4*>(dst + 4) = o1;
        return;
    }

    // ---- h_prime part (R8-verified) ----
    const int blk = blockIdx.x - 512;
    const int b   = blk >> 7;
    const int n0  = (blk & 127) * 8;

    {
        const float* src = h + ((size_t)b * N + n0) * FIN;
        float4 x = reinterpret_cast<const float4*>(src)[t];
        int fl = t * 4;
        *reinterpret_cast<float4*>(&h_lds[fl >> 7][fl & 127]) = x;
    }
    __syncthreads();

    const int hd   = t >> 6;
    const int lane = t & 63;
    const int li   = lane & 15;
    const int f0   = li * 4;
    const int g    = (lane >> 4) & 1;
    const int kh   = lane >> 5;

    float acc[4][4];
    #pragma unroll
    for (int k = 0; k < 4; ++k)
        #pragma unroll
        for (int j = 0; j < 4; ++j) acc[k][j] = 0.f;

    const float* Wp = W + (size_t)hd * FIN * FOUT + (size_t)kh * 64 * FOUT + f0;
    #pragma unroll 4
    for (int i = 0; i < 64; ++i) {
        float4 w4 = *reinterpret_cast<const float4*>(Wp + (size_t)i * FOUT);
        #pragma unroll
        for (int k = 0; k < 4; ++k) {
            float hv = h_lds[4 * g + k][kh * 64 + i];
            acc[k][0] = fmaf(hv, w4.x, acc[k][0]);
            acc[k][1] = fmaf(hv, w4.y, acc[k][1]);
            acc[k][2] = fmaf(hv, w4.z, acc[k][2]);
            acc[k][3] = fmaf(hv, w4.w, acc[k][3]);
        }
    }

    #pragma unroll
    for (int k = 0; k < 4; ++k)
        #pragma unroll
        for (int j = 0; j < 4; ++j)
            acc[k][j] += __shfl_xor(acc[k][j], 32, 64);

    const int bh = b * H + hd;
    if (kh == 0) {
        const int jc  = n0 >> 5;
        const int kgp = (n0 >> 3) & 3;
        const int ft  = li >> 2;
        const int e0  = 4 * g;
        #pragma unroll
        for (int jj = 0; jj < 4; ++jj) {
            short4v v4;
            v4[0] = (short)f2bf(acc[0][jj]);
            v4[1] = (short)f2bf(acc[1][jj]);
            v4[2] = (short)f2bf(acc[2][jj]);
            v4[3] = (short)f2bf(acc[3][jj]);
            const int lanep = (4 * (li & 3) + jj) + 16 * kgp;
            *reinterpret_cast<short4v*>(
                hpF + ((((size_t)bh * 32 + jc) * 4 + ft) * 64 + lanep) * 8 + e0) = v4;
        }
    }

    float4 a1 = *reinterpret_cast<const float4*>(a + (size_t)hd * 2 * FOUT + f0);
    float4 a2 = *reinterpret_cast<const float4*>(a + (size_t)hd * 2 * FOUT + FOUT + f0);
    #pragma unroll
    for (int k = 0; k < 4; ++k) {
        float e1 = acc[k][0] * a1.x + acc[k][1] * a1.y + acc[k][2] * a1.z + acc[k][3] * a1.w;
        float e2 = acc[k][0] * a2.x + acc[k][1] * a2.y + acc[k][2] * a2.z + acc[k][3] * a2.w;
        #pragma unroll
        for (int m = 1; m < 16; m <<= 1) {
            e1 += __shfl_xor(e1, m, 64);
            e2 += __shfl_xor(e2, m, 64);
        }
        if ((lane & 15) == 0 && kh == 0) {
            int r = n0 + 4 * g + k;
            ei_t[(size_t)bh * N + r] = LOG2E * e1;
            ej_t[(size_t)bh * N + r] = LOG2E * e2;
        }
    }
}

// ---------------------------------------------------------------------------
// Kernel B: fused scores+softmax+PV. 512 threads = 8 waves: wave = (i-tile
// w=0..3, j-half jh). Each wave runs 16 fragment-order chunks over its
// j-half (coalesced base+lane*const loads, depth-1 prefetch, c4 ones-MFMA
// row sums). j-halves combined via conflict-free LDS red[5][4][64] (lane
// stride 16B) + one barrier; jh==0 waves normalize & store. 4 waves/SIMD.
// ---------------------------------------------------------------------------
__global__ __launch_bounds__(512) void gat_attn(
    const unsigned short* __restrict__ hpF, // fragment-order bf16
    const float* __restrict__ ei_t,         // (B,H,N) *LOG2E
    const float* __restrict__ ej_t,         // (B,H,N) *LOG2E
    const float* __restrict__ mbF,          // fragment-order f32
    float* __restrict__ out)                // (B,N,H*FOUT)
{
    __shared__ f32x4 red[5][4][64];         // 20KB, [cidx][tile][lane]
    const int raw  = blockIdx.x;            // 512
    const int xcd  = raw & 7;
    const int k_   = raw >> 3;
    const int bh   = ((xcd >> 1) << 3) | (k_ >> 3);          // 8 bh per XCD
    const int it0  = (((xcd & 1) << 3) | (k_ & 7)) * 4;      // 4 i-tiles/block
    const int t    = threadIdx.x;
    const int w8   = t >> 6;
    const int w    = w8 & 3;                // i-tile
    const int jh   = w8 >> 2;               // j-half
    const int lane = t & 63;
    const int li   = lane & 15;
    const int kg   = lane >> 4;
    const int ti   = it0 + w;
    const int irow = ti * 16 + li;
    const int jcb  = jh * 16;               // first chunk of this wave's half

    const float  ei0   = ei_t[(size_t)bh * N + irow];
    const float* ejrow = ej_t + (size_t)bh * N;
    const float* mrow  = mbF + ((size_t)ti * 32 * 64 + lane) * 8;        // + jc*512
    const unsigned short* hrow = hpF + ((size_t)bh * 32 * 4 * 64 + lane) * 8; // + jc*2048 + ft*512

    f32x4 c0 = {0.f,0.f,0.f,0.f}, c1 = {0.f,0.f,0.f,0.f};
    f32x4 c2 = {0.f,0.f,0.f,0.f}, c3 = {0.f,0.f,0.f,0.f};
    f32x4 c4 = {0.f,0.f,0.f,0.f};
    const short obf = (short)0x3F80;                      // bf16 1.0
    const short8 ones = {obf,obf,obf,obf,obf,obf,obf,obf};

    #define DECLS(S) float4 ejA##S, ejB##S, mA##S, mB##S; \
                     short8 bA##S, bB##S, bC##S, bD##S;
    #define LOADS(S, JC) {                                                   \
        ejA##S = *reinterpret_cast<const float4*>(ejrow + (JC) * 32 + 8 * kg);\
        ejB##S = *reinterpret_cast<const float4*>(ejrow + (JC) * 32 + 8 * kg + 4);\
        mA##S  = *reinterpret_cast<const float4*>(mrow + (JC) * 512);        \
        mB##S  = *reinterpret_cast<const float4*>(mrow + (JC) * 512 + 4);    \
        bA##S  = *reinterpret_cast<const short8*>(hrow + (JC) * 2048);       \
        bB##S  = *reinterpret_cast<const short8*>(hrow + (JC) * 2048 + 512); \
        bC##S  = *reinterpret_cast<const short8*>(hrow + (JC) * 2048 + 1024);\
        bD##S  = *reinterpret_cast<const short8*>(hrow + (JC) * 2048 + 1536); }
    #define SCORE(PD, EJ, MBV) {                                             \
        float e_ = ei0 + (EJ);                                               \
        e_ = fmaxf(e_, 0.2f * e_) + (MBV);                                   \
        asm("v_exp_f32 %0, %1" : "=v"(PD) : "v"(e_)); }
    #define COMPS(S) {                                                       \
        float p0,p1,p2,p3,p4,p5,p6,p7;                                       \
        SCORE(p0, ejA##S.x, mA##S.x) SCORE(p1, ejA##S.y, mA##S.y)            \
        SCORE(p2, ejA##S.z, mA##S.z) SCORE(p3, ejA##S.w, mA##S.w)            \
        SCORE(p4, ejB##S.x, mB##S.x) SCORE(p5, ejB##S.y, mB##S.y)            \
        SCORE(p6, ejB##S.z, mB##S.z) SCORE(p7, ejB##S.w, mB##S.w)            \
        int4 pk_;                                                            \
        asm("v_cvt_pk_bf16_f32 %0, %1, %2" : "=v"(pk_.x) : "v"(p0), "v"(p1));\
        asm("v_cvt_pk_bf16_f32 %0, %1, %2" : "=v"(pk_.y) : "v"(p2), "v"(p3));\
        asm("v_cvt_pk_bf16_f32 %0, %1, %2" : "=v"(pk_.z) : "v"(p4), "v"(p5));\
        asm("v_cvt_pk_bf16_f32 %0, %1, %2" : "=v"(pk_.w) : "v"(p6), "v"(p7));\
        short8 a0_ = *reinterpret_cast<short8*>(&pk_);                       \
        c0 = __builtin_amdgcn_mfma_f32_16x16x32_bf16(a0_, bA##S, c0, 0,0,0); \
        c1 = __builtin_amdgcn_mfma_f32_16x16x32_bf16(a0_, bB##S, c1, 0,0,0); \
        c2 = __builtin_amdgcn_mfma_f32_16x16x32_bf16(a0_, bC##S, c2, 0,0,0); \
        c3 = __builtin_amdgcn_mfma_f32_16x16x32_bf16(a0_, bD##S, c3, 0,0,0); \
        c4 = __builtin_amdgcn_mfma_f32_16x16x32_bf16(a0_, ones,  c4, 0,0,0); }

    DECLS(0) DECLS(1)
    LOADS(0, jcb)
    #pragma unroll 2
    for (int jc = 0; jc < 16; jc += 2) {
        LOADS(1, jcb + jc + 1)
        COMPS(0)
        if (jc + 2 < 16) LOADS(0, jcb + jc + 2)
        COMPS(1)
    }
    #undef DECLS
    #undef LOADS
    #undef SCORE
    #undef COMPS

    // combine j-halves: jh==1 dumps partials, jh==0 adds + finishes.
    if (jh == 1) {
        red[0][w][lane] = c0;
        red[1][w][lane] = c1;
        red[2][w][lane] = c2;
        red[3][w][lane] = c3;
        red[4][w][lane] = c4;
    }
    __syncthreads();
    if (jh == 1) return;

    c0 += red[0][w][lane];
    c1 += red[1][w][lane];
    c2 += red[2][w][lane];
    c3 += red[3][w][lane];
    c4 += red[4][w][lane];

    // C layout col=li (f within tile), row=4*kg+r; c4[r] = that row's sum.
    const int b  = bh >> 2;
    const int hd = bh & 3;
    #pragma unroll
    for (int r = 0; r < 4; ++r) {
        int orow = ti * 16 + 4 * kg + r;
        float inv = 1.0f / c4[r];
        float* ob = out + (((size_t)b * N + orow) * H + hd) * 64 + li;
        ob[0]  = c0[r] * inv;
        ob[16] = c1[r] * inv;
        ob[32] = c2[r] * inv;
        ob[48] = c3[r] * inv;
    }
}

extern "C" void kernel_launch(void* const* d_in, const int* in_sizes, int n_in,
                              void* d_out, int out_size, void* d_ws, size_t ws_size,
                              hipStream_t stream) {
    const float* h    = (const float*)d_in[0];
    const int*   adj  = (const int*)  d_in[1];
    const float* bias = (const float*)d_in[2];
    const float* W    = (const float*)d_in[3];
    const float* a    = (const float*)d_in[4];
    float* out = (float*)d_out;

    char* ws = (char*)d_ws;
    unsigned short* hpF = (unsigned short*)ws;                    // 4 MB
    float* mbF  = (float*)(ws + (size_t)B * H * 64 * N * 2);      // 4 MB
    float* ei_t = (float*)(ws + (size_t)B * H * 64 * N * 2 + (size_t)N * N * 4);
    float* ej_t = ei_t + (size_t)B * H * N;

    gat_prep<<<512 + B * N / 8, 256, 0, stream>>>(h, W, a, adj, bias,
                                                  hpF, mbF, ei_t, ej_t);
    gat_attn<<<B * H * (N / 64), 512, 0, stream>>>(hpF, ei_t, ej_t, mbF, out);
}

// Round 11
// 38.110 us; speedup vs baseline: 1.9323x; 1.1169x over previous
//
#include <hip/hip_runtime.h>

constexpr int B = 8, N = 1024, FIN = 128, FOUT = 64, H = 4;
constexpr float LOG2E = 1.44269504f;

typedef __attribute__((ext_vector_type(8))) short short8;
typedef __attribute__((ext_vector_type(4))) short short4v;
typedef __attribute__((ext_vector_type(4))) float f32x4;

// f32 -> bf16 round-to-nearest-even (prep-kernel use only)
static __device__ inline unsigned short f2bf(float x) {
    union { float f; unsigned u; } v; v.f = x;
    unsigned r = v.u + 0x7fff + ((v.u >> 16) & 1);
    return (unsigned short)(r >> 16);
}

// ---------------------------------------------------------------------------
// Fused prep kernel. Blocks 0..511: mbB (A-fragment-order masked bias, BF16
// with -1e35 sentinel for masked edges — survives bf16, exp2 -> 0).
// Blocks 512..1535: h_prime GEMM + ei/ej (verbatim R8/R9-verified math).
//   mbB[ti][jc][lane][e] bf16 = (i=ti*16+(lane&15), j=jc*32+8*(lane>>4)+e)
//   hpF[bh][jc][ft][lane][e] bf16 = hp(f=ft*16+(lane&15), n=jc*32+8*(lane>>4)+e)
// ---------------------------------------------------------------------------
__global__ __launch_bounds__(256) void gat_prep(
    const float* __restrict__ h,      // (B,N,FIN)
    const float* __restrict__ W,      // (H,FIN,FOUT)
    const float* __restrict__ a,      // (H,2*FOUT,1)
    const int*   __restrict__ adj,    // (N,N)
    const float* __restrict__ bias,   // (N,N)
    unsigned short* __restrict__ hpF, // fragment-order bf16 (4 MB)
    unsigned short* __restrict__ mbB, // fragment-order bf16 (2 MB)
    float* __restrict__ ei_t,         // (B,H,N) *LOG2E
    float* __restrict__ ej_t)         // (B,H,N) *LOG2E
{
    __shared__ float h_lds[8][132];
    const int t = threadIdx.x;

    if (blockIdx.x < 512) {           // ---- mb part ----
        const int bx   = blockIdx.x;
        const int ti   = bx >> 3;
        const int jc   = (bx & 7) * 4 + (t >> 6);
        const int lane = t & 63;
        const int i    = ti * 16 + (lane & 15);
        const int j0   = jc * 32 + 8 * (lane >> 4);

        const int4*   ap = reinterpret_cast<const int4*>(adj + (size_t)i * N + j0);
        const float4* bp = reinterpret_cast<const float4*>(bias + (size_t)i * N + j0);
        int4   a0 = ap[0], a1 = ap[1];
        float4 b0 = bp[0], b1 = bp[1];
        unsigned short q0 = f2bf(a0.x ? LOG2E * b0.x : -1e35f);
        unsigned short q1 = f2bf(a0.y ? LOG2E * b0.y : -1e35f);
        unsigned short q2 = f2bf(a0.z ? LOG2E * b0.z : -1e35f);
        unsigned short q3 = f2bf(a0.w ? LOG2E * b0.w : -1e35f);
        unsigned short q4 = f2bf(a1.x ? LOG2E * b1.x : -1e35f);
        unsigned short q5 = f2bf(a1.y ? LOG2E * b1.y : -1e35f);
        unsigned short q6 = f2bf(a1.z ? LOG2E * b1.z : -1e35f);
        unsigned short q7 = f2bf(a1.w ? LOG2E * b1.w : -1e35f);
        int4 ov;
        ov.x = (int)((unsigned)q0 | ((unsigned)q1 << 16));
        ov.y = (int)((unsigned)q2 | ((unsigned)q3 << 16));
        ov.z = (int)((unsigned)q4 | ((unsigned)q5 << 16));
        ov.w = (int)((unsigned)q6 | ((unsigned)q7 << 16));
        *reinterpret_cast<int4*>(mbB + (((size_t)ti * 32 + jc) * 64 + lane) * 8) = ov;
        return;
    }

    // ---- h_prime part (R8/R9-verified, verbatim) ----
    const int blk = blockIdx.x - 512;
    const int b   = blk >> 7;
    const int n0  = (blk & 127) * 8;

    {
        const float* src = h + ((size_t)b * N + n0) * FIN;
        float4 x = reinterpret_cast<const float4*>(src)[t];
        int fl = t * 4;
        *reinterpret_cast<float4*>(&h_lds[fl >> 7][fl & 127]) = x;
    }
    __syncthreads();

    const int hd   = t >> 6;
    const int lane = t & 63;
    const int li   = lane & 15;
    const int f0   = li * 4;
    const int g    = (lane >> 4) & 1;
    const int kh   = lane >> 5;

    float acc[4][4];
    #pragma unroll
    for (int k = 0; k < 4; ++k)
        #pragma unroll
        for (int j = 0; j < 4; ++j) acc[k][j] = 0.f;

    const float* Wp = W + (size_t)hd * FIN * FOUT + (size_t)kh * 64 * FOUT + f0;
    #pragma unroll 4
    for (int i = 0; i < 64; ++i) {
        float4 w4 = *reinterpret_cast<const float4*>(Wp + (size_t)i * FOUT);
        #pragma unroll
        for (int k = 0; k < 4; ++k) {
            float hv = h_lds[4 * g + k][kh * 64 + i];
            acc[k][0] = fmaf(hv, w4.x, acc[k][0]);
            acc[k][1] = fmaf(hv, w4.y, acc[k][1]);
            acc[k][2] = fmaf(hv, w4.z, acc[k][2]);
            acc[k][3] = fmaf(hv, w4.w, acc[k][3]);
        }
    }

    #pragma unroll
    for (int k = 0; k < 4; ++k)
        #pragma unroll
        for (int j = 0; j < 4; ++j)
            acc[k][j] += __shfl_xor(acc[k][j], 32, 64);

    const int bh = b * H + hd;
    if (kh == 0) {
        const int jc  = n0 >> 5;
        const int kgp = (n0 >> 3) & 3;
        const int ft  = li >> 2;
        const int e0  = 4 * g;
        #pragma unroll
        for (int jj = 0; jj < 4; ++jj) {
            short4v v4;
            v4[0] = (short)f2bf(acc[0][jj]);
            v4[1] = (short)f2bf(acc[1][jj]);
            v4[2] = (short)f2bf(acc[2][jj]);
            v4[3] = (short)f2bf(acc[3][jj]);
            const int lanep = (4 * (li & 3) + jj) + 16 * kgp;
            *reinterpret_cast<short4v*>(
                hpF + ((((size_t)bh * 32 + jc) * 4 + ft) * 64 + lanep) * 8 + e0) = v4;
        }
    }

    float4 a1 = *reinterpret_cast<const float4*>(a + (size_t)hd * 2 * FOUT + f0);
    float4 a2 = *reinterpret_cast<const float4*>(a + (size_t)hd * 2 * FOUT + FOUT + f0);
    #pragma unroll
    for (int k = 0; k < 4; ++k) {
        float e1 = acc[k][0] * a1.x + acc[k][1] * a1.y + acc[k][2] * a1.z + acc[k][3] * a1.w;
        float e2 = acc[k][0] * a2.x + acc[k][1] * a2.y + acc[k][2] * a2.z + acc[k][3] * a2.w;
        #pragma unroll
        for (int m = 1; m < 16; m <<= 1) {
            e1 += __shfl_xor(e1, m, 64);
            e2 += __shfl_xor(e2, m, 64);
        }
        if ((lane & 15) == 0 && kh == 0) {
            int r = n0 + 4 * g + k;
            ei_t[(size_t)bh * N + r] = LOG2E * e1;
            ej_t[(size_t)bh * N + r] = LOG2E * e2;
        }
    }
}

// ---------------------------------------------------------------------------
// Kernel B: fused scores+softmax+PV. 512 threads = 8 waves = (i-tile w, j-half
// jh). hpF chunks staged into LDS ONCE per (jh,chunk) via global_load_lds
// (wave (w,jh) stages f-tile w; fragment layout is linear lane*16B = exactly
// the wave-uniform-dest constraint), double-buffered, one barrier per chunk;
// all 4 i-tile waves ds_read_b128 from LDS -> 4x fewer hpF bytes through L1.
// mbB is bf16 (expand = integer <<16), sentinel -1e35 -> exp2 = 0.
// c4 ones-MFMA row sums -> register-local normalization (R9-verified).
// ---------------------------------------------------------------------------
__global__ __launch_bounds__(512) void gat_attn(
    const unsigned short* __restrict__ hpF, // fragment-order bf16
    const float* __restrict__ ei_t,         // (B,H,N) *LOG2E
    const float* __restrict__ ej_t,         // (B,H,N) *LOG2E
    const unsigned short* __restrict__ mbB, // fragment-order bf16 masked bias
    float* __restrict__ out)                // (B,N,H*FOUT)
{
    __shared__ __align__(16) unsigned short hstage[2][2][4][512]; // 16KB [buf][jh][ft][lane*8+e]
    __shared__ f32x4 red[5][4][64];                               // 20KB
    const int raw  = blockIdx.x;            // 512
    const int xcd  = raw & 7;
    const int k_   = raw >> 3;
    const int bh   = ((xcd >> 1) << 3) | (k_ >> 3);          // 8 bh per XCD
    const int it0  = (((xcd & 1) << 3) | (k_ & 7)) * 4;      // 4 i-tiles/block
    const int t    = threadIdx.x;
    const int w8   = t >> 6;
    const int w    = w8 & 3;                // i-tile (also: f-tile this wave stages)
    const int jh   = w8 >> 2;               // j-half
    const int lane = t & 63;
    const int li   = lane & 15;
    const int kg   = lane >> 4;
    const int ti   = it0 + w;
    const int irow = ti * 16 + li;
    const int jcb  = jh * 16;               // first chunk of this wave's half

    const float  ei0   = ei_t[(size_t)bh * N + irow];
    const float* ejrow = ej_t + (size_t)bh * N;
    const unsigned short* mrow = mbB + ((size_t)ti * 32 * 64 + lane) * 8;  // + jc*512
    const size_t hbase = (size_t)bh * 65536;                               // u16/slab

    f32x4 c0 = {0.f,0.f,0.f,0.f}, c1 = {0.f,0.f,0.f,0.f};
    f32x4 c2 = {0.f,0.f,0.f,0.f}, c3 = {0.f,0.f,0.f,0.f};
    f32x4 c4 = {0.f,0.f,0.f,0.f};
    const short obf = (short)0x3F80;                      // bf16 1.0
    const short8 ones = {obf,obf,obf,obf,obf,obf,obf,obf};

    // stage f-tile w of chunk JCG into hstage[BUF][jh][w]
    #define STAGE(BUF, JCG) {                                                 \
        const unsigned short* gs_ = hpF + hbase + (size_t)(JCG) * 2048        \
                                        + (size_t)w * 512 + (size_t)lane * 8; \
        __builtin_amdgcn_global_load_lds(                                     \
            (const __attribute__((address_space(1))) void*)gs_,               \
            (__attribute__((address_space(3))) void*)&hstage[BUF][jh][w][0],  \
            16, 0, 0); }

    #define DSREAD(BUF, BA, BB, BC, BD) {                                     \
        BA = *reinterpret_cast<const short8*>(&hstage[BUF][jh][0][lane * 8]); \
        BB = *reinterpret_cast<const short8*>(&hstage[BUF][jh][1][lane * 8]); \
        BC = *reinterpret_cast<const short8*>(&hstage[BUF][jh][2][lane * 8]); \
        BD = *reinterpret_cast<const short8*>(&hstage[BUF][jh][3][lane * 8]); }

    // two scores from one packed-bf16 word (lo = even elem, hi = odd elem)
    #define SCORE2(PL, PH, EJL, EJH, QW) {                                    \
        float bl_ = __uint_as_float(((unsigned)(QW)) << 16);                  \
        float bh_ = __uint_as_float(((unsigned)(QW)) & 0xffff0000u);          \
        float el_ = ei0 + (EJL); el_ = fmaxf(el_, 0.2f * el_) + bl_;          \
        float eh_ = ei0 + (EJH); eh_ = fmaxf(eh_, 0.2f * eh_) + bh_;          \
        asm("v_exp_f32 %0, %1" : "=v"(PL) : "v"(el_));                        \
        asm("v_exp_f32 %0, %1" : "=v"(PH) : "v"(eh_)); }

    #define COMPS(MQ, BA, BB, BC, BD, JC) {                                   \
        float4 ejA = *reinterpret_cast<const float4*>(ejrow + (JC) * 32 + 8 * kg);     \
        float4 ejB = *reinterpret_cast<const float4*>(ejrow + (JC) * 32 + 8 * kg + 4); \
        float p0,p1,p2,p3,p4,p5,p6,p7;                                        \
        SCORE2(p0, p1, ejA.x, ejA.y, MQ.x)                                    \
        SCORE2(p2, p3, ejA.z, ejA.w, MQ.y)                                    \
        SCORE2(p4, p5, ejB.x, ejB.y, MQ.z)                                    \
        SCORE2(p6, p7, ejB.z, ejB.w, MQ.w)                                    \
        int4 pk_;                                                             \
        asm("v_cvt_pk_bf16_f32 %0, %1, %2" : "=v"(pk_.x) : "v"(p0), "v"(p1)); \
        asm("v_cvt_pk_bf16_f32 %0, %1, %2" : "=v"(pk_.y) : "v"(p2), "v"(p3)); \
        asm("v_cvt_pk_bf16_f32 %0, %1, %2" : "=v"(pk_.z) : "v"(p4), "v"(p5)); \
        asm("v_cvt_pk_bf16_f32 %0, %1, %2" : "=v"(pk_.w) : "v"(p6), "v"(p7)); \
        short8 a0_ = *reinterpret_cast<short8*>(&pk_);                        \
        c0 = __builtin_amdgcn_mfma_f32_16x16x32_bf16(a0_, BA, c0, 0, 0, 0);   \
        c1 = __builtin_amdgcn_mfma_f32_16x16x32_bf16(a0_, BB, c1, 0, 0, 0);   \
        c2 = __builtin_amdgcn_mfma_f32_16x16x32_bf16(a0_, BC, c2, 0, 0, 0);   \
        c3 = __builtin_amdgcn_mfma_f32_16x16x32_bf16(a0_, BD, c3, 0, 0, 0);   \
        c4 = __builtin_amdgcn_mfma_f32_16x16x32_bf16(a0_, ones, c4, 0, 0, 0); }

    short8 A0, B0, C0, D0, A1, B1, C1, D1;
    int4 mq0, mq1;

    STAGE(0, jcb)
    mq0 = *reinterpret_cast<const int4*>(mrow + (size_t)jcb * 512);
    __syncthreads();                         // stage(0) visible

    for (int jc = 0; jc < 16; jc += 2) {
        // --- half A: consume buf0/mq0, prefetch buf1/mq1 ---
        STAGE(1, jcb + jc + 1)
        mq1 = *reinterpret_cast<const int4*>(mrow + (size_t)(jcb + jc + 1) * 512);
        DSREAD(0, A0, B0, C0, D0)
        COMPS(mq0, A0, B0, C0, D0, jcb + jc)
        __syncthreads();                     // stage(1) visible; buf0 free
        // --- half B: consume buf1/mq1, prefetch buf0/mq0 ---
        if (jc + 2 < 16) {
            STAGE(0, jcb + jc + 2)
            mq0 = *reinterpret_cast<const int4*>(mrow + (size_t)(jcb + jc + 2) * 512);
        }
        DSREAD(1, A1, B1, C1, D1)
        COMPS(mq1, A1, B1, C1, D1, jcb + jc + 1)
        __syncthreads();                     // stage(0) visible; buf1 free
    }
    #undef STAGE
    #undef DSREAD
    #undef SCORE2
    #undef COMPS

    // combine j-halves: jh==1 dumps partials, jh==0 adds + finishes.
    if (jh == 1) {
        red[0][w][lane] = c0;
        red[1][w][lane] = c1;
        red[2][w][lane] = c2;
        red[3][w][lane] = c3;
        red[4][w][lane] = c4;
    }
    __syncthreads();
    if (jh == 1) return;

    c0 += red[0][w][lane];
    c1 += red[1][w][lane];
    c2 += red[2][w][lane];
    c3 += red[3][w][lane];
    c4 += red[4][w][lane];

    // C layout col=li (f within tile), row=4*kg+r; c4[r] = that row's sum.
    const int b  = bh >> 2;
    const int hd = bh & 3;
    #pragma unroll
    for (int r = 0; r < 4; ++r) {
        int orow = ti * 16 + 4 * kg + r;
        float inv = 1.0f / c4[r];
        float* ob = out + (((size_t)b * N + orow) * H + hd) * 64 + li;
        ob[0]  = c0[r] * inv;
        ob[16] = c1[r] * inv;
        ob[32] = c2[r] * inv;
        ob[48] = c3[r] * inv;
    }
}

extern "C" void kernel_launch(void* const* d_in, const int* in_sizes, int n_in,
                              void* d_out, int out_size, void* d_ws, size_t ws_size,
                              hipStream_t stream) {
    const float* h    = (const float*)d_in[0];
    const int*   adj  = (const int*)  d_in[1];
    const float* bias = (const float*)d_in[2];
    const float* W    = (const float*)d_in[3];
    const float* a    = (const float*)d_in[4];
    float* out = (float*)d_out;

    char* ws = (char*)d_ws;
    unsigned short* hpF = (unsigned short*)ws;                        // 4 MB
    unsigned short* mbB = (unsigned short*)(ws + ((size_t)4 << 20));  // 2 MB
    float* ei_t = (float*)(ws + ((size_t)6 << 20));                   // 128 KB
    float* ej_t = ei_t + (size_t)B * H * N;                           // 128 KB

    gat_prep<<<512 + B * N / 8, 256, 0, stream>>>(h, W, a, adj, bias,
                                                  hpF, mbB, ei_t, ej_t);
    gat_attn<<<B * H * (N / 64), 512, 0, stream>>>(hpF, ei_t, ej_t, mbB, out);
}